// Round 2
// 25679.504 us; speedup vs baseline: 1.0203x; 1.0203x over previous
//
#include <hip/hip_runtime.h>

// ============================================================================
// Two-level LSTM (char k-mer LSTM -> word LSTM), MI355X.
//
// Persistent multi-WG recurrence kernels, all worker WGs elected onto ONE XCD
// (pigeonhole election, HW_REG_XCC_ID).
//
// R9 protocol (fixes R8's hang):
//  * Publish (proven since R4): tagged 8-byte slots ((t+1)<<32|f32bits(h)),
//    parity double-buffered, global_atomic_swap_x2 (executes at the TCC).
//  * Poll: __hip_atomic_load(RELAXED, AGENT) -- the SAME builtin the role
//    election has been spinning on since R4, which provably observes remote
//    atomic writes (election terminates every round, even cross-XCD). R8's
//    hand-rolled `sc0` load hung: on gfx940+ the {sc1,sc0} bits are a scope
//    field (0=CU,1=SE,2=Device,3=System); agent scope is sc1, NOT sc0 -- an
//    SE-scope load may be served by a cache level TCC atomics never
//    invalidate. Delegate flag selection to the compiler.
//  * SINGLE slot copy (replicas removed): replicas existed (R7) because 256
//    RMW-pollers per line serialized at the TCC; load-pollers don't RMW, so
//    concurrent readers of one line are cheap. Producer publishes 16
//    swaps/WG-step (was 256 fan-out). Per-step TCC RMW count: ~14K -> 256
//    (char) / 512 (word). R7's WRITE_SIZE=1.5GB ~= 8B x RMW-count
//    (write-through atomics) predicts WRITE_SIZE -> ~40MB.
//
// Race-freedom (R4 argument, unchanged): WG g publishes tag t+1 only after
// all its threads passed the post-poll barrier of step t. Every WG
// collectively polls ALL producers' slots each step; a producer publishing
// tag t+1 therefore implies every WG completed its step-t poll, so
// overwriting the same-parity tag-(t-1) slot is safe. Same-lane same-address
// swaps (t, t+2) are ordered by the intervening step-t+1 poll: vmcnt retires
// in issue order, so completing the poll load drains the earlier swap (plus
// an explicit s_waitcnt vmcnt(0) after each poll loop as insurance).
// Stale slots from a previous bench iteration hold tags {16383,16384} (char)
// / {4095,4096} (word); polls ascend from tag 1 and each slot is overwritten
// before the polled tag can reach the stale value -> no false positive.
// ============================================================================

#define S_LEN 4096
#define TCH   16384
#define ALPHA 25
#define ECH   64
#define HR    256
#define DL    128
#define EW    128
#define HW    512
#define NWC   16           // char worker WGs (16 units each)
#define GRIDC 128
#define NWW   32           // word worker WGs (16 units each)
#define GRIDW 256

static __device__ __forceinline__ float fsigmoid(float x) {
  x = fminf(fmaxf(x, -30.f), 30.f);
  return __builtin_amdgcn_rcpf(1.0f + __expf(-x));
}
static __device__ __forceinline__ float ftanh(float x) {
  x = fminf(fmaxf(x, -15.f), 15.f);
  float e = __expf(2.0f * x);
  return 1.0f - 2.0f * __builtin_amdgcn_rcpf(e + 1.0f);
}

static __device__ __forceinline__ void barrier_lds() {
  asm volatile("s_waitcnt lgkmcnt(0)\n\ts_barrier" ::: "memory");
}
// Coherent 8-byte poll read: agent-scope relaxed atomic load. Identical
// codegen path to elect_role's spin -- the harness-proven coherent read.
static __device__ __forceinline__ unsigned long long poll_slot(
    const unsigned long long* p) {
  return __hip_atomic_load(p, __ATOMIC_RELAXED, __HIP_MEMORY_SCOPE_AGENT);
}
// Atomic swap, no return: fire-and-forget commit at the TCC.
static __device__ __forceinline__ void atom_swap(
    unsigned long long* p, unsigned long long v) {
  asm volatile("global_atomic_swap_x2 %0, %1, off" :: "v"(p), "v"(v) : "memory");
}
static __device__ __forceinline__ void drain_vm() {
  asm volatile("s_waitcnt vmcnt(0)" ::: "memory");
}

// Deadlock-free single-XCD role election (R4-proven).
static __device__ __forceinline__ int elect_role(int* el, int NW) {
  unsigned xcd;
  asm volatile("s_getreg_b32 %0, hwreg(HW_REG_XCC_ID)" : "=s"(xcd));
  xcd &= 7u;
  int r = __hip_atomic_fetch_add(&el[xcd], 1, __ATOMIC_RELAXED,
                                 __HIP_MEMORY_SCOPE_AGENT);
  if (r == NW - 1) {
    int exp = -1;
    __hip_atomic_compare_exchange_strong(&el[8], &exp, (int)xcd,
        __ATOMIC_RELAXED, __ATOMIC_RELAXED, __HIP_MEMORY_SCOPE_AGENT);
  }
  int w;
  while ((w = __hip_atomic_load(&el[8], __ATOMIC_RELAXED,
                                __HIP_MEMORY_SCOPE_AGENT)) < 0) {}
  if (w != (int)xcd) return -1;
  int rr = __hip_atomic_fetch_add(&el[9], 1, __ATOMIC_RELAXED,
                                  __HIP_MEMORY_SCOPE_AGENT);
  return (rr < NW) ? rr : -1;
}

__global__ void k_init(int* ec, int* ew) {
  int t = threadIdx.x;
  if (t < 10) ec[t] = (t == 8) ? -1 : 0;
  else if (t < 20) { int u = t - 10; ew[u] = (u == 8) ? -1 : 0; }
}

// ---------------------------------------------------------------------------
// K1a: char gate-input table: table[a][row] = b_r[row] + E_char[a,:]·W_ih_r[row,:]
// ---------------------------------------------------------------------------
__global__ void k_table(const float* __restrict__ Ec, const float* __restrict__ Wih,
                        const float* __restrict__ br, float* __restrict__ table) {
  __shared__ __align__(16) float e[ECH];
  int a = blockIdx.x, tid = threadIdx.x;
  if (tid < ECH) e[tid] = Ec[a * ECH + tid];
  __syncthreads();
  for (int row = tid; row < 4 * HR; row += 256) {
    const float4* w = (const float4*)(Wih + row * ECH);
    const float4* e4 = (const float4*)e;
    float acc = 0.f;
#pragma unroll
    for (int j = 0; j < ECH / 4; ++j) {
      float4 wv = w[j], ev = e4[j];
      acc += wv.x * ev.x + wv.y * ev.y + wv.z * ev.z + wv.w * ev.w;
    }
    table[a * (4 * HR) + row] = acc + br[row];
  }
}

// ---------------------------------------------------------------------------
// K1b: permute W_ih_w k-major: WT[k][p], p = wg*64 + (gate*16 + unit).
// ---------------------------------------------------------------------------
__global__ void k_permw(const float* __restrict__ Wihw, const float* __restrict__ bw,
                        float* __restrict__ WT, float* __restrict__ bperm) {
  int e = blockIdx.x * 256 + threadIdx.x;
  int p = e >> 8, k = e & 255;
  int r = p & 63, wgp = p >> 6;
  int R = (r >> 4) * HW + wgp * 16 + (r & 15);
  WT[k * (4 * HW) + p] = Wihw[R * (EW + DL) + k];
  if (k == 0) bperm[p] = bw[R];
}

// ---------------------------------------------------------------------------
// K2: persistent char LSTM. 16 WGs x 256 threads on one XCD.
// slots: SINGLE copy, [parity][element 0..255], 8 B tagged words.
// Thread tid polls slots[par][tid]; producer wave0 lanes<16 publish 16 swaps.
// ---------------------------------------------------------------------------
__global__ __launch_bounds__(256, 1) void k_char_lstm(
    const int* __restrict__ char_ids, const float* __restrict__ Whh,
    const float* __restrict__ table, unsigned long long* __restrict__ slots,
    int* __restrict__ elect, float* __restrict__ h_word)
{
  __shared__ int role_sh;
  if (threadIdx.x == 0) role_sh = elect_role(elect, NWC);
  __syncthreads();
  const int wg = role_sh;
  if (wg < 0) return;

  const int tid = threadIdx.x;
  const int wave = tid >> 6, lane = tid & 63;
  const int R = (lane >> 4) * HR + wg * 16 + (lane & 15);
  float4 wreg[16];
  {
    const float4* wp = (const float4*)(Whh + R * HR + wave * 64);
#pragma unroll
    for (int j = 0; j < 16; ++j) wreg[j] = wp[j];
  }
  __shared__ __align__(16) float tab[ALPHA * 64];
  __shared__ __align__(16) float hst[4][64];
  __shared__ __align__(16) float part[2][4][64];
  for (int i = tid; i < ALPHA * 64; i += 256) {
    int chh = i >> 6, r = i & 63;
    int Rr = (r >> 4) * HR + wg * 16 + (r & 15);
    tab[i] = table[chh * (4 * HR) + Rr];
  }
  hst[wave][lane] = 0.f;
  float creg = 0.f;                      // cell state: wave0 lanes<16
  __syncthreads();

#pragma unroll 1
  for (int t = 0; t < TCH; ++t) {
    int ch = char_ids[t];
    if (t > 0) {
      // poll the single shared copy with agent-scope atomic loads (no RMW)
      const unsigned long long* sl = slots + ((t - 1) & 1) * HR + tid;
      unsigned long long v;
      do { v = poll_slot(sl); } while ((unsigned)(v >> 32) != (unsigned)t);
      drain_vm();                        // orders prior swaps across parities
      hst[wave][lane] = __uint_as_float((unsigned)v);
      // same-wave LDS write->read: compiler-inserted lgkmcnt, no barrier.
    }
    const float4* hp = (const float4*)hst[wave];
    float a0 = 0.f, a1 = 0.f, a2 = 0.f, a3 = 0.f;
#pragma unroll
    for (int j = 0; j < 4; ++j) {
      float4 h0 = hp[4*j+0], h1 = hp[4*j+1], h2 = hp[4*j+2], h3 = hp[4*j+3];
      float4 w0 = wreg[4*j+0], w1 = wreg[4*j+1], w2 = wreg[4*j+2], w3 = wreg[4*j+3];
      a0 += w0.x*h0.x + w0.y*h0.y + w0.z*h0.z + w0.w*h0.w;
      a1 += w1.x*h1.x + w1.y*h1.y + w1.z*h1.z + w1.w*h1.w;
      a2 += w2.x*h2.x + w2.y*h2.y + w2.z*h2.z + w2.w*h2.w;
      a3 += w3.x*h3.x + w3.y*h3.y + w3.z*h3.z + w3.w*h3.w;
    }
    const int par = t & 1;
    part[par][wave][lane] = (a0 + a1) + (a2 + a3);
    barrier_lds();                       // single barrier per step
    if (wave == 0) {
      float z = ((part[par][0][lane] + part[par][1][lane]) +
                 (part[par][2][lane] + part[par][3][lane])) + tab[ch * 64 + lane];
      int u = lane & 15;
      float zi = __shfl(z, u,      64);
      float zf = __shfl(z, u + 16, 64);
      float zg = __shfl(z, u + 32, 64);
      float zo = __shfl(z, u + 48, 64);
      if (lane < 16) {
        float ig = fsigmoid(zi), fg = fsigmoid(zf), og = fsigmoid(zo);
        float gg = ftanh(zg);
        creg = fg * creg + ig * gg;
        float h = og * ftanh(creg);
        unsigned long long pv =
            (((unsigned long long)(unsigned)(t + 1)) << 32) |
            (unsigned long long)__float_as_uint(h);
        atom_swap(slots + par * HR + wg * 16 + lane, pv);
        if ((t & 3) == 3)
          h_word[(t >> 2) * HR + wg * 16 + lane] = h;
      }
    }
  }
}

// ---------------------------------------------------------------------------
// K3a: latent = tanh(h_word @ W_lat^T + b_lat).
// ---------------------------------------------------------------------------
__global__ __launch_bounds__(128) void k_latent(
    const float* __restrict__ hw, const float* __restrict__ Wlat,
    const float* __restrict__ blat, float* __restrict__ lat)
{
  int t = blockIdx.x, d = threadIdx.x;
  __shared__ __align__(16) float hh[HR];
  ((float2*)hh)[d] = ((const float2*)(hw + t * HR))[d];
  __syncthreads();
  const float4* w = (const float4*)(Wlat + d * HR);
  const float4* h4 = (const float4*)hh;
  float acc = 0.f;
#pragma unroll 8
  for (int j = 0; j < HR / 4; ++j) {
    float4 wv = w[j], hv = h4[j];
    acc += wv.x * hv.x + wv.y * hv.y + wv.z * hv.z + wv.w * hv.w;
  }
  lat[t * DL + d] = tanhf(acc + blat[d]);
}

// ---------------------------------------------------------------------------
// K3b: Xw[t][p] = bperm[p] + concat(E_word[wid[t]], latent[t]) · W row(p)
// ---------------------------------------------------------------------------
__global__ __launch_bounds__(256) void k_xw(
    const float* __restrict__ Ew, const int* __restrict__ wid,
    const float* __restrict__ lat, const float* __restrict__ WT,
    const float* __restrict__ bperm, float* __restrict__ Xw)
{
  int tblk = blockIdx.x, pblk = blockIdx.y;
  int tid = threadIdx.x;
  int p = pblk * 256 + tid;
  __shared__ __align__(16) float xt[32][256];
  int t0 = tblk * 32;
  for (int i = tid; i < 32 * 256; i += 256) {
    int tl = i >> 8, e = i & 255;
    int t = t0 + tl;
    float v;
    if (e < 128) v = Ew[wid[t] * EW + e];
    else         v = lat[t * DL + (e - 128)];
    xt[tl][e] = v;
  }
  __syncthreads();
  float acc[32];
#pragma unroll
  for (int i = 0; i < 32; ++i) acc[i] = 0.f;
  for (int k = 0; k < 256; k += 4) {
    float w0 = WT[(k + 0) * (4 * HW) + p];
    float w1 = WT[(k + 1) * (4 * HW) + p];
    float w2 = WT[(k + 2) * (4 * HW) + p];
    float w3 = WT[(k + 3) * (4 * HW) + p];
#pragma unroll
    for (int tl = 0; tl < 32; ++tl) {
      float4 x4 = *(const float4*)&xt[tl][k];
      acc[tl] += w0 * x4.x + w1 * x4.y + w2 * x4.z + w3 * x4.w;
    }
  }
  float b = bperm[p];
#pragma unroll
  for (int tl = 0; tl < 32; ++tl)
    Xw[(t0 + tl) * (4 * HW) + p] = acc[tl] + b;
}

// ---------------------------------------------------------------------------
// K4: persistent word LSTM. 32 WGs x 512 threads (8 waves) on one XCD.
// Wave w = k-segment [64w, 64w+64); lane: gate=lane>>4, unit=lane&15.
// slots: SINGLE copy, [parity][element 0..511], 8 B tagged words.
// ---------------------------------------------------------------------------
__global__ __launch_bounds__(512, 1) void k_word_lstm(
    const float* __restrict__ Whh, const float* __restrict__ Xw,
    unsigned long long* __restrict__ slots, int* __restrict__ elect,
    float* __restrict__ out)
{
  __shared__ int role_sh;
  if (threadIdx.x == 0) role_sh = elect_role(elect, NWW);
  __syncthreads();
  const int wg = role_sh;
  if (wg < 0) return;

  const int tid = threadIdx.x;
  const int wave = tid >> 6, lane = tid & 63;
  const int R = (lane >> 4) * HW + wg * 16 + (lane & 15);
  float4 wreg[16];
  {
    const float4* wp = (const float4*)(Whh + R * HW + wave * 64);
#pragma unroll
    for (int j = 0; j < 16; ++j) wreg[j] = wp[j];
  }
  __shared__ __align__(16) float hst[8][64];
  __shared__ __align__(16) float part[2][8][64];
  hst[wave][lane] = 0.f;
  float creg = 0.f;                      // cell state: wave0 lanes<16
  __syncthreads();
  float xv = 0.f;
  if (wave == 0) xv = Xw[wg * 64 + lane];

#pragma unroll 1
  for (int t = 0; t < S_LEN; ++t) {
    float xn = 0.f;
    if (wave == 0) {                     // prefetch next x-slice
      int tt = (t + 1 < S_LEN) ? (t + 1) : t;
      xn = Xw[tt * (4 * HW) + wg * 64 + lane];
    }
    if (t > 0) {
      const unsigned long long* sl = slots + ((t - 1) & 1) * HW + tid;
      unsigned long long v;
      do { v = poll_slot(sl); } while ((unsigned)(v >> 32) != (unsigned)t);
      drain_vm();
      hst[wave][lane] = __uint_as_float((unsigned)v);
    }
    const float4* hp = (const float4*)hst[wave];
    float a0 = 0.f, a1 = 0.f, a2 = 0.f, a3 = 0.f;
#pragma unroll
    for (int j = 0; j < 4; ++j) {
      float4 h0 = hp[4*j+0], h1 = hp[4*j+1], h2 = hp[4*j+2], h3 = hp[4*j+3];
      float4 w0 = wreg[4*j+0], w1 = wreg[4*j+1], w2 = wreg[4*j+2], w3 = wreg[4*j+3];
      a0 += w0.x*h0.x + w0.y*h0.y + w0.z*h0.z + w0.w*h0.w;
      a1 += w1.x*h1.x + w1.y*h1.y + w1.z*h1.z + w1.w*h1.w;
      a2 += w2.x*h2.x + w2.y*h2.y + w2.z*h2.z + w2.w*h2.w;
      a3 += w3.x*h3.x + w3.y*h3.y + w3.z*h3.z + w3.w*h3.w;
    }
    const int par = t & 1;
    part[par][wave][lane] = (a0 + a1) + (a2 + a3);
    barrier_lds();
    if (wave == 0) {
      float z = (((part[par][0][lane] + part[par][1][lane]) +
                  (part[par][2][lane] + part[par][3][lane])) +
                 ((part[par][4][lane] + part[par][5][lane]) +
                  (part[par][6][lane] + part[par][7][lane]))) + xv;
      int u = lane & 15;
      float zi = __shfl(z, u,      64);
      float zf = __shfl(z, u + 16, 64);
      float zg = __shfl(z, u + 32, 64);
      float zo = __shfl(z, u + 48, 64);
      if (lane < 16) {
        float ig = fsigmoid(zi), fg = fsigmoid(zf), og = fsigmoid(zo);
        float gg = ftanh(zg);
        creg = fg * creg + ig * gg;
        float h = og * ftanh(creg);
        unsigned long long pv =
            (((unsigned long long)(unsigned)(t + 1)) << 32) |
            (unsigned long long)__float_as_uint(h);
        atom_swap(slots + par * HW + wg * 16 + lane, pv);
        out[t * HW + wg * 16 + lane] = h;
      }
      xv = xn;
    }
  }
}

// ---------------------------------------------------------------------------
extern "C" void kernel_launch(void* const* d_in, const int* in_sizes, int n_in,
                              void* d_out, int out_size, void* d_ws, size_t ws_size,
                              hipStream_t stream) {
  const float* E_char = (const float*)d_in[0];
  const float* W_ih_r = (const float*)d_in[1];
  const float* W_hh_r = (const float*)d_in[2];
  const float* b_r    = (const float*)d_in[3];
  const float* W_lat  = (const float*)d_in[4];
  const float* b_lat  = (const float*)d_in[5];
  const float* E_word = (const float*)d_in[6];
  const float* W_ih_w = (const float*)d_in[7];
  const float* W_hh_w = (const float*)d_in[8];
  const float* b_w    = (const float*)d_in[9];
  const int* word_ids = (const int*)d_in[10];
  const int* char_ids = (const int*)d_in[11];

  char* ws = (char*)d_ws;
  float*              tableR = (float*)(ws + 0x000000);              // 100 KB
  int*                electC = (int*)(ws + 0x020000);
  int*                electW = (int*)(ws + 0x020100);
  unsigned long long* slotC  = (unsigned long long*)(ws + 0x030000); // 4 KB
  unsigned long long* slotW  = (unsigned long long*)(ws + 0x050000); // 8 KB
  float*              h_word = (float*)(ws + 0x100000);              // 4 MB
  float*              latent = (float*)(ws + 0x500000);              // 2 MB
  float*              WT     = (float*)(ws + 0x700000);              // 2 MB
  float*              bperm  = (float*)(ws + 0x900000);              // 8 KB
  float*              Xw     = (float*)(ws + 0xA00000);              // 32 MB
  float* out = (float*)d_out;

  hipLaunchKernelGGL(k_init,      dim3(1),      dim3(64),  0, stream,
                     electC, electW);
  hipLaunchKernelGGL(k_table,     dim3(ALPHA),  dim3(256), 0, stream,
                     E_char, W_ih_r, b_r, tableR);
  hipLaunchKernelGGL(k_permw,     dim3(2048),   dim3(256), 0, stream,
                     W_ih_w, b_w, WT, bperm);
  hipLaunchKernelGGL(k_char_lstm, dim3(GRIDC),  dim3(256), 0, stream,
                     char_ids, W_hh_r, tableR, slotC, electC, h_word);
  hipLaunchKernelGGL(k_latent,    dim3(S_LEN),  dim3(128), 0, stream,
                     h_word, W_lat, b_lat, latent);
  hipLaunchKernelGGL(k_xw,        dim3(128, 8), dim3(256), 0, stream,
                     E_word, word_ids, latent, WT, bperm, Xw);
  hipLaunchKernelGGL(k_word_lstm, dim3(GRIDW),  dim3(512), 0, stream,
                     W_hh_w, Xw, slotW, electW, out);
}